// Round 8
// baseline (335.224 us; speedup 1.0000x reference)
//
#include <hip/hip_runtime.h>
#include <hip/hip_cooperative_groups.h>

namespace cg = cooperative_groups;

// Reverb via FFT overlap-save cross-correlation. R8: cooperative mega-kernel,
// hardened after R7's silent coop-launch failure (unchecked error, grid too
// large for co-residency). Math = R5 (133.5us verified): 3-pass
// radix-256/256/16 Stockham, L=2^20, conflict-free LDS (strides===1 mod 16).
//  - grid sized from hipOccupancyMaxActiveBlocksPerMultiprocessor
//  - all phases grid-stride (any grid size correct)
//  - no registers held across grid.sync (phase 7 recomputes final dft16;
//    also kills norm_fused's 21MB r+w)
//  - fallback: R5's verified 7-kernel sequence if coop unavailable/fails

#define L_FFT (1 << 20)
#define GSTRIDE 273

__device__ __forceinline__ float2 cmul(float2 a, float2 b) {
    return make_float2(a.x * b.x - a.y * b.y, a.x * b.y + a.y * b.x);
}

__device__ __forceinline__ void rad4(float2 a, float2 b, float2 c, float2 d,
                                     float2& o0, float2& o1, float2& o2, float2& o3) {
    float2 apc = make_float2(a.x + c.x, a.y + c.y);
    float2 amc = make_float2(a.x - c.x, a.y - c.y);
    float2 bpd = make_float2(b.x + d.x, b.y + d.y);
    float2 bmd = make_float2(b.x - d.x, b.y - d.y);
    o0 = make_float2(apc.x + bpd.x, apc.y + bpd.y);
    o2 = make_float2(apc.x - bpd.x, apc.y - bpd.y);
    o1 = make_float2(amc.x + bmd.y, amc.y - bmd.x);
    o3 = make_float2(amc.x - bmd.y, amc.y + bmd.x);
}

// 16-pt DFT, natural order in/out (bench-verified R2-R6).
__device__ __forceinline__ void dft16(float2 x[16]) {
    float2 tt[16];
    rad4(x[0], x[4], x[8],  x[12], tt[0],  tt[1],  tt[2],  tt[3]);
    rad4(x[1], x[5], x[9],  x[13], tt[4],  tt[5],  tt[6],  tt[7]);
    rad4(x[2], x[6], x[10], x[14], tt[8],  tt[9],  tt[10], tt[11]);
    rad4(x[3], x[7], x[11], x[15], tt[12], tt[13], tt[14], tt[15]);
    const float C1 = 0.92387953251128675613f, S1 = 0.38268343236508977173f;
    const float C2 = 0.70710678118654752440f;
    const float2 W1 = make_float2( C1, -S1);
    const float2 W2 = make_float2( C2, -C2);
    const float2 W3 = make_float2( S1, -C1);
    const float2 W6 = make_float2(-C2, -C2);
    const float2 W9 = make_float2(-C1,  S1);
    tt[5]  = cmul(tt[5],  W1);
    tt[6]  = cmul(tt[6],  W2);
    tt[7]  = cmul(tt[7],  W3);
    tt[9]  = cmul(tt[9],  W2);
    tt[10] = make_float2(tt[10].y, -tt[10].x);
    tt[11] = cmul(tt[11], W6);
    tt[13] = cmul(tt[13], W3);
    tt[14] = cmul(tt[14], W6);
    tt[15] = cmul(tt[15], W9);
    rad4(tt[0], tt[4], tt[8],  tt[12], x[0], x[4], x[8],  x[12]);
    rad4(tt[1], tt[5], tt[9],  tt[13], x[1], x[5], x[9],  x[13]);
    rad4(tt[2], tt[6], tt[10], tt[14], x[2], x[6], x[10], x[14]);
    rad4(tt[3], tt[7], tt[11], tt[15], x[3], x[7], x[11], x[15]);
}

__device__ __forceinline__ void fft256_core(float2 x[16], int i, int gi,
                                            float2* lds) {
    dft16(x);
    float sa, ca;
    __sincosf(-6.28318530717958647692f * (float)i * (1.0f / 256.0f), &sa, &ca);
    float2 w1 = make_float2(ca, sa);
    float2 w = w1;
#pragma unroll
    for (int k1 = 1; k1 < 16; ++k1) {
        x[k1] = cmul(x[k1], w);
        w = cmul(w, w1);
    }
    float2* base = lds + gi * GSTRIDE;
#pragma unroll
    for (int k1 = 0; k1 < 16; ++k1) base[i * 17 + k1] = x[k1];
    __syncthreads();
#pragma unroll
    for (int q1 = 0; q1 < 16; ++q1) x[q1] = base[q1 * 17 + i];
    dft16(x);
}

__device__ __forceinline__ void stage256_store(float2 x[16], float2* db,
                                               int g, int i, int J, int log2J,
                                               float invLn) {
    int j = g & (J - 1);
    int np = g >> log2J;
    float base = -6.28318530717958647692f * (float)np * invLn;
    float sa, ca;
    __sincosf(base * (float)i, &sa, &ca);
    float2 w = make_float2(ca, sa);
    __sincosf(base * 16.0f, &sa, &ca);
    float2 w16 = make_float2(ca, sa);
    size_t ob = (size_t)256 * (g - j) + j;
#pragma unroll
    for (int k2 = 0; k2 < 16; ++k2) {
        db[ob + (size_t)(i + 16 * k2) * J] = cmul(x[k2], w);
        w = cmul(w, w16);
    }
}

__device__ __forceinline__ void unit_pack_fwd1(const float* audio, const float* ir,
                                               float2* B, int u, int tid,
                                               float2* lds, int N, int M, int V,
                                               float invL) {
    int bx = u & 255, slot = u >> 8;
    int gi = tid & 15, i = tid >> 4;
    int g = bx * 16 + gi;
    float2* db = B + (size_t)slot * L_FFT;
    float2 x[16];
#pragma unroll
    for (int q2 = 0; q2 < 16; ++q2) {
        int idx = g + (i + 16 * q2) * (L_FFT / 256);
        float2 v;
        if (slot == 0) {
            v = make_float2(audio[idx], audio[idx + V]);
        } else if (slot == 1) {
            float a2 = (idx + 2 * V < N) ? audio[idx + 2 * V] : 0.f;
            float a3 = (idx + 3 * V < N) ? audio[idx + 3 * V] : 0.f;
            v = make_float2(a2, a3);
        } else {
            v = make_float2((idx < M) ? ir[idx] : 0.f, 0.f);
        }
        x[q2] = v;
    }
    fft256_core(x, i, gi, lds);
    stage256_store(x, db, g, i, 1, 0, invL);
}

__device__ __forceinline__ void unit_stage256(const float2* src, float2* dst,
                                              int u, int tid, int J, int log2J,
                                              float invLn, float2* lds) {
    int bx = u & 255, slot = u >> 8;
    int gi = tid & 15, i = tid >> 4;
    int g = bx * 16 + gi;
    const float2* sb = src + (size_t)slot * L_FFT;
    float2* db = dst + (size_t)slot * L_FFT;
    float2 x[16];
#pragma unroll
    for (int q2 = 0; q2 < 16; ++q2)
        x[q2] = sb[g + (i + 16 * q2) * (L_FFT / 256)];
    fft256_core(x, i, gi, lds);
    stage256_store(x, db, g, i, J, log2J, invLn);
}

__device__ __forceinline__ void unit_fwd3_spectral(const float2* A, float2* B,
                                                   int u, int tid, float2* XS) {
    int isFwd = (tid < 128);
    int j = isFwd ? tid : (tid - 128);
    int gf = u * 128 + j;
    int g = isFwd ? gf : ((65536 - gf) & 65535);
    int ptid = isFwd ? (tid + 128) : (tid - 128);

    float2 h[16];
#pragma unroll
    for (int q = 0; q < 16; ++q)
        h[q] = A[(size_t)2 * L_FFT + g + (size_t)q * 65536];
    dft16(h);
#pragma unroll
    for (int p = 0; p < 2; ++p) {
        float2 x[16];
#pragma unroll
        for (int q = 0; q < 16; ++q)
            x[q] = A[(size_t)p * L_FFT + g + (size_t)q * 65536];
        dft16(x);
        __syncthreads();
#pragma unroll
        for (int r = 0; r < 16; ++r) XS[tid * 17 + r] = x[r];
        __syncthreads();
#pragma unroll
        for (int r = 0; r < 16; ++r) {
            int mi = (g == 0) ? ((16 - r) & 15) : (15 - r);
            float2 Z  = x[r];
            float2 Zr = XS[ptid * 17 + mi];
            float2 H  = h[r];
            float2 X0 = make_float2(0.5f * (Z.x + Zr.x), 0.5f * (Z.y - Zr.y));
            float2 X1 = make_float2(0.5f * (Z.y + Zr.y), 0.5f * (Zr.x - Z.x));
            float2 G0 = make_float2(X0.x * H.x + X0.y * H.y, X0.y * H.x - X0.x * H.y);
            float2 G1 = make_float2(X1.x * H.x + X1.y * H.y, X1.y * H.x - X1.x * H.y);
            B[(size_t)p * L_FFT + g + (size_t)r * 65536] =
                make_float2(G0.x - G1.y, -(G0.y + G1.x));   // conj(P)
        }
    }
}

// ================= cooperative mega-kernel =================
__global__ __launch_bounds__(256) void reverb_mega(
    const float* __restrict__ audio, const float* __restrict__ ir,
    float* __restrict__ out, float2* __restrict__ A, float2* __restrict__ B,
    float* __restrict__ partials, int N, int M, int V) {
    __shared__ __align__(16) float2 lds[16 * GSTRIDE];
    __shared__ float sm[4];
    cg::grid_group grid = cg::this_grid();
    const int tid = threadIdx.x;
    const int bid = blockIdx.x;
    const int G = gridDim.x;
    const float invL   = 1.0f / (float)L_FFT;
    const float invLn2 = 1.0f / 4096.0f;

    // phase 1: pack + forward J=1 -> B (768 units)
    for (int u = bid; u < 768; u += G) {
        __syncthreads();   // LDS reuse guard between units
        unit_pack_fwd1(audio, ir, B, u, tid, lds, N, M, V, invL);
    }
    grid.sync();
    // phase 2: forward J=256: B -> A (768 units)
    for (int u = bid; u < 768; u += G) {
        __syncthreads();
        unit_stage256(B, A, u, tid, 256, 8, invLn2, lds);
    }
    grid.sync();
    // phase 3: fwd final radix-16 + spectral: A -> B slots 0,1 (257 units)
    for (int u = bid; u < 257; u += G)
        unit_fwd3_spectral(A, B, u, tid, lds);   // internal barriers guard LDS
    grid.sync();
    // phase 4: inverse J=1: B -> A (512 units)
    for (int u = bid; u < 512; u += G) {
        __syncthreads();
        unit_stage256(B, A, u, tid, 1, 0, invL, lds);
    }
    grid.sync();
    // phase 5: inverse J=256: A -> B (512 units)
    for (int u = bid; u < 512; u += G) {
        __syncthreads();
        unit_stage256(A, B, u, tid, 256, 8, invLn2, lds);
    }
    grid.sync();
    // phase 6: final radix-16 (registers, no store) -> block max partials
    for (int u = bid; u < 512; u += G) {
        int p = u >> 8;
        int g = (u & 255) * 256 + tid;
        int lenO = (p == 1) ? (N - 3 * V) : V;
        const float2* sb = B + (size_t)p * L_FFT;
        float2 x[16];
#pragma unroll
        for (int q = 0; q < 16; ++q) x[q] = sb[g + q * 65536];
        dft16(x);
        float m = 0.f;
#pragma unroll
        for (int r = 0; r < 16; ++r) {
            int n = g + r * 65536;
            if (n < V)    m = fmaxf(m, fabsf(x[r].x));
            if (n < lenO) m = fmaxf(m, fabsf(x[r].y));
        }
        for (int o = 32; o > 0; o >>= 1) m = fmaxf(m, __shfl_xor(m, o));
        int lane = tid & 63, wv = tid >> 6;
        if (lane == 0) sm[wv] = m;
        __syncthreads();
        if (tid == 0)
            partials[u] = fmaxf(fmaxf(sm[0], sm[1]), fmaxf(sm[2], sm[3]));
        __syncthreads();
    }
    grid.sync();
    // phase 7: reduce partials per block, recompute final dft16, write out
    {
        float m = 0.f;
        for (int i = tid; i < 512; i += 256) m = fmaxf(m, partials[i]);
        for (int o = 32; o > 0; o >>= 1) m = fmaxf(m, __shfl_xor(m, o));
        int lane = tid & 63, wv = tid >> 6;
        if (lane == 0) sm[wv] = m;
        __syncthreads();
        float inv = 1.0f / fmaxf(fmaxf(sm[0], sm[1]), fmaxf(sm[2], sm[3]));
        for (int u = bid; u < 512; u += G) {
            int p = u >> 8;
            int g = (u & 255) * 256 + tid;
            int lenO = (p == 1) ? (N - 3 * V) : V;
            int se = 2 * p, so = 2 * p + 1;
            const float2* sb = B + (size_t)p * L_FFT;
            float2 x[16];
#pragma unroll
            for (int q = 0; q < 16; ++q) x[q] = sb[g + q * 65536];
            dft16(x);
#pragma unroll
            for (int r = 0; r < 16; ++r) {
                int n = g + r * 65536;
                if (n < V)    out[(size_t)se * V + n] = x[r].x * inv;
                if (n < lenO) out[(size_t)so * V + n] = -x[r].y * inv;
            }
        }
    }
}

// ================= R5 fallback kernels (verified, 133.5us) =================
__global__ void fb_fwd1_pack(const float* __restrict__ audio,
                             const float* __restrict__ ir,
                             float2* __restrict__ dst, int N, int M, int V) {
    __shared__ float2 lds[16 * GSTRIDE];
    int tid = threadIdx.x;
    unit_pack_fwd1(audio, ir, dst, blockIdx.y * 256 + blockIdx.x, tid, lds,
                   N, M, V, 1.0f / (float)L_FFT);
}

__global__ void fb_stage256(const float2* __restrict__ src, float2* __restrict__ dst,
                            int J, int log2J, float invLn) {
    __shared__ float2 lds[16 * GSTRIDE];
    unit_stage256(src, dst, blockIdx.y * 256 + blockIdx.x, threadIdx.x,
                  J, log2J, invLn, lds);
}

__global__ void fb_fwd3_spectral(const float2* __restrict__ A,
                                 float2* __restrict__ B) {
    __shared__ float2 XS[256 * 17];
    unit_fwd3_spectral(A, B, blockIdx.x, threadIdx.x, XS);
}

__global__ void fb_inv3_out(const float2* __restrict__ src, float* __restrict__ out,
                            float* __restrict__ partials, int N, int V) {
    int g = blockIdx.x * blockDim.x + threadIdx.x;
    int p = blockIdx.y;
    const float2* sb = src + (size_t)p * L_FFT;
    float2 x[16];
#pragma unroll
    for (int q = 0; q < 16; ++q) x[q] = sb[g + q * 65536];
    dft16(x);
    int se = 2 * p, so = 2 * p + 1;
    int lenO = (p == 1) ? (N - 3 * V) : V;
    float m = 0.f;
#pragma unroll
    for (int r = 0; r < 16; ++r) {
        int n = g + r * 65536;
        float vr = x[r].x, vi = -x[r].y;
        if (n < V)    { out[(size_t)se * V + n] = vr; m = fmaxf(m, fabsf(vr)); }
        if (n < lenO) { out[(size_t)so * V + n] = vi; m = fmaxf(m, fabsf(vi)); }
    }
    for (int o = 32; o > 0; o >>= 1) m = fmaxf(m, __shfl_xor(m, o));
    __shared__ float sm[4];
    int lane = threadIdx.x & 63, wv = threadIdx.x >> 6;
    if (lane == 0) sm[wv] = m;
    __syncthreads();
    if (threadIdx.x == 0)
        partials[blockIdx.y * gridDim.x + blockIdx.x] =
            fmaxf(fmaxf(sm[0], sm[1]), fmaxf(sm[2], sm[3]));
}

__global__ void fb_norm_fused(float* __restrict__ out,
                              const float* __restrict__ partials, int N) {
    float m = 0.f;
    for (int i = threadIdx.x; i < 512; i += 256) m = fmaxf(m, partials[i]);
    for (int o = 32; o > 0; o >>= 1) m = fmaxf(m, __shfl_xor(m, o));
    __shared__ float sm[4];
    int lane = threadIdx.x & 63, wv = threadIdx.x >> 6;
    if (lane == 0) sm[wv] = m;
    __syncthreads();
    float inv = 1.0f / fmaxf(fmaxf(sm[0], sm[1]), fmaxf(sm[2], sm[3]));
    int stride = gridDim.x * blockDim.x;
    for (int t = blockIdx.x * blockDim.x + threadIdx.x; t < N; t += stride)
        out[t] *= inv;
}

extern "C" void kernel_launch(void* const* d_in, const int* in_sizes, int n_in,
                              void* d_out, int out_size, void* d_ws, size_t ws_size,
                              hipStream_t stream) {
    const float* audio = (const float*)d_in[0];
    const float* ir    = (const float*)d_in[1];
    float* out = (float*)d_out;

    int N = in_sizes[0];          // 2,646,000
    int M = in_sizes[1];          // 220,500
    int V = L_FFT - M + 1;        // 828,077

    float2* A = (float2*)d_ws;
    float2* B = A + (size_t)3 * L_FFT;
    float* partials = (float*)(B + (size_t)3 * L_FFT);

    // Capture-safe host queries (no stream ops, deterministic every call).
    int dev = 0;
    hipGetDevice(&dev);
    hipDeviceProp_t prop;
    hipError_t e1 = hipGetDeviceProperties(&prop, dev);
    int occ = 0;
    hipError_t e2 = hipOccupancyMaxActiveBlocksPerMultiprocessor(
        &occ, (const void*)reverb_mega, 256, 0);

    bool tryCoop = (e1 == hipSuccess) && (e2 == hipSuccess) &&
                   (prop.cooperativeLaunch != 0) && (occ >= 1);
    hipError_t ce = hipErrorUnknown;
    if (tryCoop) {
        int grid = occ * prop.multiProcessorCount;
        if (grid > 768) grid = 768;
        void* args[] = {(void*)&audio, (void*)&ir, (void*)&out, (void*)&A,
                        (void*)&B, (void*)&partials, (void*)&N, (void*)&M,
                        (void*)&V};
        ce = hipLaunchCooperativeKernel((const void*)reverb_mega, dim3(grid),
                                        dim3(256), args, 0, stream);
    }
    if (ce != hipSuccess) {
        // R5 fallback (verified path)
        const float invL   = 1.0f / (float)L_FFT;
        const float invLn2 = 1.0f / 4096.0f;
        fb_fwd1_pack<<<dim3(256, 3), 256, 0, stream>>>(audio, ir, B, N, M, V);
        fb_stage256<<<dim3(256, 3), 256, 0, stream>>>(B, A, 256, 8, invLn2);
        fb_fwd3_spectral<<<257, 256, 0, stream>>>(A, B);
        fb_stage256<<<dim3(256, 2), 256, 0, stream>>>(B, A, 1, 0, invL);
        fb_stage256<<<dim3(256, 2), 256, 0, stream>>>(A, B, 256, 8, invLn2);
        fb_inv3_out<<<dim3(256, 2), 256, 0, stream>>>(B, out, partials, N, V);
        fb_norm_fused<<<1024, 256, 0, stream>>>(out, partials, N);
    }
}

// Round 9
// 130.746 us; speedup vs baseline: 2.5639x; 2.5639x over previous
//
#include <hip/hip_runtime.h>

// Reverb via FFT overlap-save cross-correlation. R9 = R5 (133.5us champion)
// + coalesced J=1 stores. R8 post-mortem: coop grid.sync costs 100s of us on
// 8 XCDs -> multi-kernel path is the substrate. R9 theory: the two J=1
// passes stored at 32B-per-instruction granularity (db[256g + i+16k2]:
// 16x32B chunks @2KB stride per instr) — the only sub-line streams left.
// Fix: route through LDS (pad e+(e>>8): bank-pair=(gi+i)%16 -> 4-way b64
// floor) and store block-contiguous 32KB windows in 512B/wave runs.
// Everything else is bit-identical R5.

#define L_FFT (1 << 20)
#define GSTRIDE 273

__device__ __forceinline__ float2 cmul(float2 a, float2 b) {
    return make_float2(a.x * b.x - a.y * b.y, a.x * b.y + a.y * b.x);
}

__device__ __forceinline__ void rad4(float2 a, float2 b, float2 c, float2 d,
                                     float2& o0, float2& o1, float2& o2, float2& o3) {
    float2 apc = make_float2(a.x + c.x, a.y + c.y);
    float2 amc = make_float2(a.x - c.x, a.y - c.y);
    float2 bpd = make_float2(b.x + d.x, b.y + d.y);
    float2 bmd = make_float2(b.x - d.x, b.y - d.y);
    o0 = make_float2(apc.x + bpd.x, apc.y + bpd.y);
    o2 = make_float2(apc.x - bpd.x, apc.y - bpd.y);
    o1 = make_float2(amc.x + bmd.y, amc.y - bmd.x);
    o3 = make_float2(amc.x - bmd.y, amc.y + bmd.x);
}

// 16-pt DFT, natural order in/out (bench-verified R2-R8).
__device__ __forceinline__ void dft16(float2 x[16]) {
    float2 tt[16];
    rad4(x[0], x[4], x[8],  x[12], tt[0],  tt[1],  tt[2],  tt[3]);
    rad4(x[1], x[5], x[9],  x[13], tt[4],  tt[5],  tt[6],  tt[7]);
    rad4(x[2], x[6], x[10], x[14], tt[8],  tt[9],  tt[10], tt[11]);
    rad4(x[3], x[7], x[11], x[15], tt[12], tt[13], tt[14], tt[15]);
    const float C1 = 0.92387953251128675613f, S1 = 0.38268343236508977173f;
    const float C2 = 0.70710678118654752440f;
    const float2 W1 = make_float2( C1, -S1);
    const float2 W2 = make_float2( C2, -C2);
    const float2 W3 = make_float2( S1, -C1);
    const float2 W6 = make_float2(-C2, -C2);
    const float2 W9 = make_float2(-C1,  S1);
    tt[5]  = cmul(tt[5],  W1);
    tt[6]  = cmul(tt[6],  W2);
    tt[7]  = cmul(tt[7],  W3);
    tt[9]  = cmul(tt[9],  W2);
    tt[10] = make_float2(tt[10].y, -tt[10].x);
    tt[11] = cmul(tt[11], W6);
    tt[13] = cmul(tt[13], W3);
    tt[14] = cmul(tt[14], W6);
    tt[15] = cmul(tt[15], W9);
    rad4(tt[0], tt[4], tt[8],  tt[12], x[0], x[4], x[8],  x[12]);
    rad4(tt[1], tt[5], tt[9],  tt[13], x[1], x[5], x[9],  x[13]);
    rad4(tt[2], tt[6], tt[10], tt[14], x[2], x[6], x[10], x[14]);
    rad4(tt[3], tt[7], tt[11], tt[15], x[3], x[7], x[11], x[15]);
}

// 256-pt FFT across a 16-thread group (strides 273/17 === 1 mod 16:
// bank-pair = gi+row+col -> 4-way b64 floor; R5-verified).
__device__ __forceinline__ void fft256_core(float2 x[16], int i, int gi,
                                            float2* lds) {
    dft16(x);
    float sa, ca;
    __sincosf(-6.28318530717958647692f * (float)i * (1.0f / 256.0f), &sa, &ca);
    float2 w1 = make_float2(ca, sa);
    float2 w = w1;
#pragma unroll
    for (int k1 = 1; k1 < 16; ++k1) {
        x[k1] = cmul(x[k1], w);
        w = cmul(w, w1);
    }
    float2* base = lds + gi * GSTRIDE;
#pragma unroll
    for (int k1 = 0; k1 < 16; ++k1) base[i * 17 + k1] = x[k1];
    __syncthreads();
#pragma unroll
    for (int q1 = 0; q1 < 16; ++q1) x[q1] = base[q1 * 17 + i];
    dft16(x);
}

// Generic stage twiddle + Stockham scatter (used by J=256 passes; 128B granule).
__device__ __forceinline__ void stage256_store(float2 x[16], float2* db,
                                               int g, int i, int J, int log2J,
                                               float invLn) {
    int j = g & (J - 1);
    int np = g >> log2J;
    float base = -6.28318530717958647692f * (float)np * invLn;
    float sa, ca;
    __sincosf(base * (float)i, &sa, &ca);
    float2 w = make_float2(ca, sa);
    __sincosf(base * 16.0f, &sa, &ca);
    float2 w16 = make_float2(ca, sa);
    size_t ob = (size_t)256 * (g - j) + j;
#pragma unroll
    for (int k2 = 0; k2 < 16; ++k2) {
        db[ob + (size_t)(i + 16 * k2) * J] = cmul(x[k2], w);
        w = cmul(w, w16);
    }
}

// J=1 store, COALESCED: twiddle w_L^{g*r}, transpose via LDS (pad e+(e>>8)),
// then block-contiguous 32KB window written in 512B/wave runs.
__device__ __forceinline__ void store_j1_coalesced(float2 x[16], float2* db,
                                                   int bx, int gi, int i, int tid,
                                                   float2* lds, float invL) {
    int g = bx * 16 + gi;
    float base = -6.28318530717958647692f * (float)g * invL;
    float sa, ca;
    __sincosf(base * (float)i, &sa, &ca);
    float2 w = make_float2(ca, sa);
    __sincosf(base * 16.0f, &sa, &ca);
    float2 w16 = make_float2(ca, sa);
    __syncthreads();                         // fft256_core lds reads done
#pragma unroll
    for (int k2 = 0; k2 < 16; ++k2) {
        int e = 256 * gi + i + 16 * k2;
        lds[e + (e >> 8)] = cmul(x[k2], w);  // bank-pair (gi+i)%16: 4-way floor
        w = cmul(w, w16);
    }
    __syncthreads();
    float2* dwin = db + (size_t)4096 * bx;
#pragma unroll
    for (int c = 0; c < 16; ++c) {
        int e2 = tid + 256 * c;
        dwin[e2] = lds[e2 + (e2 >> 8)];      // read addr t+257c: conflict-free
    }
}

// ---- K1: pack + forward J=1 (coalesced store) ----
__global__ void fwd1_pack(const float* __restrict__ audio,
                          const float* __restrict__ ir,
                          float2* __restrict__ dst, int N, int M, int V) {
    __shared__ float2 lds[16 * GSTRIDE];     // 4368 float2 >= 4112 needed
    int tid = threadIdx.x;
    int gi = tid & 15, i = tid >> 4;
    int bx = blockIdx.x, slot = blockIdx.y;
    int g = bx * 16 + gi;
    float2* db = dst + (size_t)slot * L_FFT;

    float2 x[16];
#pragma unroll
    for (int q2 = 0; q2 < 16; ++q2) {
        int idx = g + (i + 16 * q2) * (L_FFT / 256);
        float2 v;
        if (slot == 0) {
            v = make_float2(audio[idx], audio[idx + V]);
        } else if (slot == 1) {
            float a2 = (idx + 2 * V < N) ? audio[idx + 2 * V] : 0.f;
            float a3 = (idx + 3 * V < N) ? audio[idx + 3 * V] : 0.f;
            v = make_float2(a2, a3);
        } else {
            v = make_float2((idx < M) ? ir[idx] : 0.f, 0.f);
        }
        x[q2] = v;
    }
    fft256_core(x, i, gi, lds);
    store_j1_coalesced(x, db, bx, gi, i, tid, lds, 1.0f / (float)L_FFT);
}

// ---- K4: inverse J=1 (strided read, coalesced store) ----
__global__ void inv1(const float2* __restrict__ src, float2* __restrict__ dst) {
    __shared__ float2 lds[16 * GSTRIDE];
    int tid = threadIdx.x;
    int gi = tid & 15, i = tid >> 4;
    int bx = blockIdx.x;
    int g = bx * 16 + gi;
    size_t boff = (size_t)blockIdx.y * L_FFT;
    const float2* sb = src + boff;
    float2* db = dst + boff;
    float2 x[16];
#pragma unroll
    for (int q2 = 0; q2 < 16; ++q2)
        x[q2] = sb[g + (i + 16 * q2) * (L_FFT / 256)];
    fft256_core(x, i, gi, lds);
    store_j1_coalesced(x, db, bx, gi, i, tid, lds, 1.0f / (float)L_FFT);
}

// ---- K2/K5: generic radix-256 pass (J=256) ----
__global__ void stage256(const float2* __restrict__ src, float2* __restrict__ dst,
                         int J, int log2J, float invLn) {
    __shared__ float2 lds[16 * GSTRIDE];
    int tid = threadIdx.x;
    int gi = tid & 15, i = tid >> 4;
    int g = blockIdx.x * 16 + gi;
    size_t boff = (size_t)blockIdx.y * L_FFT;
    const float2* sb = src + boff;
    float2* db = dst + boff;
    float2 x[16];
#pragma unroll
    for (int q2 = 0; q2 < 16; ++q2)
        x[q2] = sb[g + (i + 16 * q2) * (L_FFT / 256)];
    fft256_core(x, i, gi, lds);
    stage256_store(x, db, g, i, J, log2J, invLn);
}

// ---- K3: fwd final radix-16 + spectral multiply (1KB-run IO; R5-verified) ----
__global__ void fwd3_spectral(const float2* __restrict__ A,
                              float2* __restrict__ B) {
    __shared__ float2 XS[256 * 17];
    int tid = threadIdx.x;
    int isFwd = (tid < 128);
    int j = isFwd ? tid : (tid - 128);
    int gf = blockIdx.x * 128 + j;
    int g = isFwd ? gf : ((65536 - gf) & 65535);
    int ptid = isFwd ? (tid + 128) : (tid - 128);

    float2 h[16];
#pragma unroll
    for (int q = 0; q < 16; ++q)
        h[q] = A[(size_t)2 * L_FFT + g + (size_t)q * 65536];
    dft16(h);
#pragma unroll
    for (int p = 0; p < 2; ++p) {
        float2 x[16];
#pragma unroll
        for (int q = 0; q < 16; ++q)
            x[q] = A[(size_t)p * L_FFT + g + (size_t)q * 65536];
        dft16(x);
        __syncthreads();
#pragma unroll
        for (int r = 0; r < 16; ++r) XS[tid * 17 + r] = x[r];
        __syncthreads();
#pragma unroll
        for (int r = 0; r < 16; ++r) {
            int mi = (g == 0) ? ((16 - r) & 15) : (15 - r);
            float2 Z  = x[r];
            float2 Zr = XS[ptid * 17 + mi];
            float2 H  = h[r];
            float2 X0 = make_float2(0.5f * (Z.x + Zr.x), 0.5f * (Z.y - Zr.y));
            float2 X1 = make_float2(0.5f * (Z.y + Zr.y), 0.5f * (Zr.x - Z.x));
            float2 G0 = make_float2(X0.x * H.x + X0.y * H.y, X0.y * H.x - X0.x * H.y);
            float2 G1 = make_float2(X1.x * H.x + X1.y * H.y, X1.y * H.x - X1.x * H.y);
            B[(size_t)p * L_FFT + g + (size_t)r * 65536] =
                make_float2(G0.x - G1.y, -(G0.y + G1.x));   // conj(P)
        }
    }
}

// ---- K6: inverse final radix-16 + slice + max partials ----
__global__ void inv3_out(const float2* __restrict__ src, float* __restrict__ out,
                         float* __restrict__ partials, int N, int V) {
    int g = blockIdx.x * blockDim.x + threadIdx.x;
    int p = blockIdx.y;
    const float2* sb = src + (size_t)p * L_FFT;
    float2 x[16];
#pragma unroll
    for (int q = 0; q < 16; ++q) x[q] = sb[g + q * 65536];
    dft16(x);
    int se = 2 * p, so = 2 * p + 1;
    int lenO = (p == 1) ? (N - 3 * V) : V;
    float m = 0.f;
#pragma unroll
    for (int r = 0; r < 16; ++r) {
        int n = g + r * 65536;
        float vr = x[r].x, vi = -x[r].y;
        if (n < V)    { out[(size_t)se * V + n] = vr; m = fmaxf(m, fabsf(vr)); }
        if (n < lenO) { out[(size_t)so * V + n] = vi; m = fmaxf(m, fabsf(vi)); }
    }
    for (int o = 32; o > 0; o >>= 1) m = fmaxf(m, __shfl_xor(m, o));
    __shared__ float sm[4];
    int lane = threadIdx.x & 63, wv = threadIdx.x >> 6;
    if (lane == 0) sm[wv] = m;
    __syncthreads();
    if (threadIdx.x == 0)
        partials[blockIdx.y * gridDim.x + blockIdx.x] =
            fmaxf(fmaxf(sm[0], sm[1]), fmaxf(sm[2], sm[3]));
}

// ---- K7: fused reduce + normalize ----
__global__ void norm_fused(float* __restrict__ out,
                           const float* __restrict__ partials, int N) {
    float m = 0.f;
    for (int i = threadIdx.x; i < 512; i += 256) m = fmaxf(m, partials[i]);
    for (int o = 32; o > 0; o >>= 1) m = fmaxf(m, __shfl_xor(m, o));
    __shared__ float sm[4];
    int lane = threadIdx.x & 63, wv = threadIdx.x >> 6;
    if (lane == 0) sm[wv] = m;
    __syncthreads();
    float inv = 1.0f / fmaxf(fmaxf(sm[0], sm[1]), fmaxf(sm[2], sm[3]));
    int stride = gridDim.x * blockDim.x;
    for (int t = blockIdx.x * blockDim.x + threadIdx.x; t < N; t += stride)
        out[t] *= inv;
}

extern "C" void kernel_launch(void* const* d_in, const int* in_sizes, int n_in,
                              void* d_out, int out_size, void* d_ws, size_t ws_size,
                              hipStream_t stream) {
    const float* audio = (const float*)d_in[0];
    const float* ir    = (const float*)d_in[1];
    float* out = (float*)d_out;

    const int N = in_sizes[0];          // 2,646,000
    const int M = in_sizes[1];          // 220,500
    const int V = L_FFT - M + 1;        // 828,077

    float2* A = (float2*)d_ws;
    float2* B = A + (size_t)3 * L_FFT;
    float* partials = (float*)(B + (size_t)3 * L_FFT);

    const float invLn2 = 1.0f / 4096.0f;

    fwd1_pack<<<dim3(256, 3), 256, 0, stream>>>(audio, ir, B, N, M, V);
    stage256<<<dim3(256, 3), 256, 0, stream>>>(B, A, 256, 8, invLn2);
    fwd3_spectral<<<257, 256, 0, stream>>>(A, B);
    inv1<<<dim3(256, 2), 256, 0, stream>>>(B, A);
    stage256<<<dim3(256, 2), 256, 0, stream>>>(A, B, 256, 8, invLn2);
    inv3_out<<<dim3(256, 2), 256, 0, stream>>>(B, out, partials, N, V);
    norm_fused<<<1024, 256, 0, stream>>>(out, partials, N);
}

// Round 11
// 125.674 us; speedup vs baseline: 2.6674x; 1.0404x over previous
//
#include <hip/hip_runtime.h>
#include <hip/hip_fp16.h>

// Reverb via FFT overlap-save cross-correlation. R11 = R10 fp16-storage
// pipeline with the scale bug fixed: conj(P) is scaled by 2^-20 (= 1/L)
// at the K3 store instead of 2^-10. R10's NaN: inverse passes grow
// magnitudes ~16x each, so final un-normalized values hit |y|*L*2^-10
// ~ 5e5 > fp16 max (65504) -> inf -> NaN. With 1/L applied up front the
// whole inverse chain stays in [1e-4, ~2e3]; the constant cancels in
// max-abs normalization. Compute fp32 throughout; structure = R9 champion.

#define L_FFT (1 << 20)
#define GSTRIDE 273
#define PSCALE (1.0f / 1048576.0f)   // 2^-20 = 1/L

__device__ __forceinline__ float2 h2f(__half2 h) { return __half22float2(h); }
__device__ __forceinline__ __half2 f2h(float2 v) { return __floats2half2_rn(v.x, v.y); }

__device__ __forceinline__ float2 cmul(float2 a, float2 b) {
    return make_float2(a.x * b.x - a.y * b.y, a.x * b.y + a.y * b.x);
}

__device__ __forceinline__ void rad4(float2 a, float2 b, float2 c, float2 d,
                                     float2& o0, float2& o1, float2& o2, float2& o3) {
    float2 apc = make_float2(a.x + c.x, a.y + c.y);
    float2 amc = make_float2(a.x - c.x, a.y - c.y);
    float2 bpd = make_float2(b.x + d.x, b.y + d.y);
    float2 bmd = make_float2(b.x - d.x, b.y - d.y);
    o0 = make_float2(apc.x + bpd.x, apc.y + bpd.y);
    o2 = make_float2(apc.x - bpd.x, apc.y - bpd.y);
    o1 = make_float2(amc.x + bmd.y, amc.y - bmd.x);
    o3 = make_float2(amc.x - bmd.y, amc.y + bmd.x);
}

// 16-pt DFT, natural order in/out (bench-verified R2-R9).
__device__ __forceinline__ void dft16(float2 x[16]) {
    float2 tt[16];
    rad4(x[0], x[4], x[8],  x[12], tt[0],  tt[1],  tt[2],  tt[3]);
    rad4(x[1], x[5], x[9],  x[13], tt[4],  tt[5],  tt[6],  tt[7]);
    rad4(x[2], x[6], x[10], x[14], tt[8],  tt[9],  tt[10], tt[11]);
    rad4(x[3], x[7], x[11], x[15], tt[12], tt[13], tt[14], tt[15]);
    const float C1 = 0.92387953251128675613f, S1 = 0.38268343236508977173f;
    const float C2 = 0.70710678118654752440f;
    const float2 W1 = make_float2( C1, -S1);
    const float2 W2 = make_float2( C2, -C2);
    const float2 W3 = make_float2( S1, -C1);
    const float2 W6 = make_float2(-C2, -C2);
    const float2 W9 = make_float2(-C1,  S1);
    tt[5]  = cmul(tt[5],  W1);
    tt[6]  = cmul(tt[6],  W2);
    tt[7]  = cmul(tt[7],  W3);
    tt[9]  = cmul(tt[9],  W2);
    tt[10] = make_float2(tt[10].y, -tt[10].x);
    tt[11] = cmul(tt[11], W6);
    tt[13] = cmul(tt[13], W3);
    tt[14] = cmul(tt[14], W6);
    tt[15] = cmul(tt[15], W9);
    rad4(tt[0], tt[4], tt[8],  tt[12], x[0], x[4], x[8],  x[12]);
    rad4(tt[1], tt[5], tt[9],  tt[13], x[1], x[5], x[9],  x[13]);
    rad4(tt[2], tt[6], tt[10], tt[14], x[2], x[6], x[10], x[14]);
    rad4(tt[3], tt[7], tt[11], tt[15], x[3], x[7], x[11], x[15]);
}

// 256-pt FFT across a 16-thread group (strides 273/17 === 1 mod 16:
// bank-pair = gi+row+col -> 4-way b64 floor; R5-verified).
__device__ __forceinline__ void fft256_core(float2 x[16], int i, int gi,
                                            float2* lds) {
    dft16(x);
    float sa, ca;
    __sincosf(-6.28318530717958647692f * (float)i * (1.0f / 256.0f), &sa, &ca);
    float2 w1 = make_float2(ca, sa);
    float2 w = w1;
#pragma unroll
    for (int k1 = 1; k1 < 16; ++k1) {
        x[k1] = cmul(x[k1], w);
        w = cmul(w, w1);
    }
    float2* base = lds + gi * GSTRIDE;
#pragma unroll
    for (int k1 = 0; k1 < 16; ++k1) base[i * 17 + k1] = x[k1];
    __syncthreads();
#pragma unroll
    for (int q1 = 0; q1 < 16; ++q1) x[q1] = base[q1 * 17 + i];
    dft16(x);
}

// Stage twiddle + Stockham scatter for J=256 passes.
__device__ __forceinline__ void stage256_store(float2 x[16], __half2* db,
                                               int g, int i, int J, int log2J,
                                               float invLn) {
    int j = g & (J - 1);
    int np = g >> log2J;
    float base = -6.28318530717958647692f * (float)np * invLn;
    float sa, ca;
    __sincosf(base * (float)i, &sa, &ca);
    float2 w = make_float2(ca, sa);
    __sincosf(base * 16.0f, &sa, &ca);
    float2 w16 = make_float2(ca, sa);
    size_t ob = (size_t)256 * (g - j) + j;
#pragma unroll
    for (int k2 = 0; k2 < 16; ++k2) {
        db[ob + (size_t)(i + 16 * k2) * J] = f2h(cmul(x[k2], w));
        w = cmul(w, w16);
    }
}

// J=1 store, coalesced via LDS (pad e+(e>>8): 4-way b64 floor), then
// block-contiguous window (R9-verified).
__device__ __forceinline__ void store_j1_coalesced(float2 x[16], __half2* db,
                                                   int bx, int gi, int i, int tid,
                                                   float2* lds, float invL) {
    int g = bx * 16 + gi;
    float base = -6.28318530717958647692f * (float)g * invL;
    float sa, ca;
    __sincosf(base * (float)i, &sa, &ca);
    float2 w = make_float2(ca, sa);
    __sincosf(base * 16.0f, &sa, &ca);
    float2 w16 = make_float2(ca, sa);
    __syncthreads();
#pragma unroll
    for (int k2 = 0; k2 < 16; ++k2) {
        int e = 256 * gi + i + 16 * k2;
        lds[e + (e >> 8)] = cmul(x[k2], w);
        w = cmul(w, w16);
    }
    __syncthreads();
    __half2* dwin = db + (size_t)4096 * bx;
#pragma unroll
    for (int c = 0; c < 16; ++c) {
        int e2 = tid + 256 * c;
        dwin[e2] = f2h(lds[e2 + (e2 >> 8)]);
    }
}

// ---- K1: pack + forward J=1 ----
__global__ void fwd1_pack(const float* __restrict__ audio,
                          const float* __restrict__ ir,
                          __half2* __restrict__ dst, int N, int M, int V) {
    __shared__ float2 lds[16 * GSTRIDE];
    int tid = threadIdx.x;
    int gi = tid & 15, i = tid >> 4;
    int bx = blockIdx.x, slot = blockIdx.y;
    int g = bx * 16 + gi;
    __half2* db = dst + (size_t)slot * L_FFT;

    float2 x[16];
#pragma unroll
    for (int q2 = 0; q2 < 16; ++q2) {
        int idx = g + (i + 16 * q2) * (L_FFT / 256);
        float2 v;
        if (slot == 0) {
            v = make_float2(audio[idx], audio[idx + V]);
        } else if (slot == 1) {
            float a2 = (idx + 2 * V < N) ? audio[idx + 2 * V] : 0.f;
            float a3 = (idx + 3 * V < N) ? audio[idx + 3 * V] : 0.f;
            v = make_float2(a2, a3);
        } else {
            v = make_float2((idx < M) ? ir[idx] : 0.f, 0.f);
        }
        x[q2] = v;
    }
    fft256_core(x, i, gi, lds);
    store_j1_coalesced(x, db, bx, gi, i, tid, lds, 1.0f / (float)L_FFT);
}

// ---- K4: inverse J=1 ----
__global__ void inv1(const __half2* __restrict__ src, __half2* __restrict__ dst) {
    __shared__ float2 lds[16 * GSTRIDE];
    int tid = threadIdx.x;
    int gi = tid & 15, i = tid >> 4;
    int bx = blockIdx.x;
    int g = bx * 16 + gi;
    size_t boff = (size_t)blockIdx.y * L_FFT;
    const __half2* sb = src + boff;
    __half2* db = dst + boff;
    float2 x[16];
#pragma unroll
    for (int q2 = 0; q2 < 16; ++q2)
        x[q2] = h2f(sb[g + (i + 16 * q2) * (L_FFT / 256)]);
    fft256_core(x, i, gi, lds);
    store_j1_coalesced(x, db, bx, gi, i, tid, lds, 1.0f / (float)L_FFT);
}

// ---- K2/K5: generic radix-256 pass (J=256) ----
__global__ void stage256(const __half2* __restrict__ src, __half2* __restrict__ dst,
                         int J, int log2J, float invLn) {
    __shared__ float2 lds[16 * GSTRIDE];
    int tid = threadIdx.x;
    int gi = tid & 15, i = tid >> 4;
    int g = blockIdx.x * 16 + gi;
    size_t boff = (size_t)blockIdx.y * L_FFT;
    const __half2* sb = src + boff;
    __half2* db = dst + boff;
    float2 x[16];
#pragma unroll
    for (int q2 = 0; q2 < 16; ++q2)
        x[q2] = h2f(sb[g + (i + 16 * q2) * (L_FFT / 256)]);
    fft256_core(x, i, gi, lds);
    stage256_store(x, db, g, i, J, log2J, invLn);
}

// ---- K3: fwd final radix-16 + spectral multiply (scale 1/L for fp16 range) ----
__global__ void fwd3_spectral(const __half2* __restrict__ A,
                              __half2* __restrict__ B) {
    __shared__ float2 XS[256 * 17];
    int tid = threadIdx.x;
    int isFwd = (tid < 128);
    int j = isFwd ? tid : (tid - 128);
    int gf = blockIdx.x * 128 + j;
    int g = isFwd ? gf : ((65536 - gf) & 65535);
    int ptid = isFwd ? (tid + 128) : (tid - 128);

    float2 h[16];
#pragma unroll
    for (int q = 0; q < 16; ++q)
        h[q] = h2f(A[(size_t)2 * L_FFT + g + (size_t)q * 65536]);
    dft16(h);
#pragma unroll
    for (int p = 0; p < 2; ++p) {
        float2 x[16];
#pragma unroll
        for (int q = 0; q < 16; ++q)
            x[q] = h2f(A[(size_t)p * L_FFT + g + (size_t)q * 65536]);
        dft16(x);
        __syncthreads();
#pragma unroll
        for (int r = 0; r < 16; ++r) XS[tid * 17 + r] = x[r];
        __syncthreads();
#pragma unroll
        for (int r = 0; r < 16; ++r) {
            int mi = (g == 0) ? ((16 - r) & 15) : (15 - r);
            float2 Z  = x[r];
            float2 Zr = XS[ptid * 17 + mi];
            float2 H  = h[r];
            float2 X0 = make_float2(0.5f * (Z.x + Zr.x), 0.5f * (Z.y - Zr.y));
            float2 X1 = make_float2(0.5f * (Z.y + Zr.y), 0.5f * (Zr.x - Z.x));
            float2 G0 = make_float2(X0.x * H.x + X0.y * H.y, X0.y * H.x - X0.x * H.y);
            float2 G1 = make_float2(X1.x * H.x + X1.y * H.y, X1.y * H.x - X1.x * H.y);
            B[(size_t)p * L_FFT + g + (size_t)r * 65536] =
                f2h(make_float2((G0.x - G1.y) * PSCALE,
                                -(G0.y + G1.x) * PSCALE));   // conj(P)/L
        }
    }
}

// ---- K6: inverse final radix-16 + slice + max partials ----
__global__ void inv3_out(const __half2* __restrict__ src, float* __restrict__ out,
                         float* __restrict__ partials, int N, int V) {
    int g = blockIdx.x * blockDim.x + threadIdx.x;
    int p = blockIdx.y;
    const __half2* sb = src + (size_t)p * L_FFT;
    float2 x[16];
#pragma unroll
    for (int q = 0; q < 16; ++q) x[q] = h2f(sb[g + q * 65536]);
    dft16(x);
    int se = 2 * p, so = 2 * p + 1;
    int lenO = (p == 1) ? (N - 3 * V) : V;
    float m = 0.f;
#pragma unroll
    for (int r = 0; r < 16; ++r) {
        int n = g + r * 65536;
        float vr = x[r].x, vi = -x[r].y;
        if (n < V)    { out[(size_t)se * V + n] = vr; m = fmaxf(m, fabsf(vr)); }
        if (n < lenO) { out[(size_t)so * V + n] = vi; m = fmaxf(m, fabsf(vi)); }
    }
    for (int o = 32; o > 0; o >>= 1) m = fmaxf(m, __shfl_xor(m, o));
    __shared__ float sm[4];
    int lane = threadIdx.x & 63, wv = threadIdx.x >> 6;
    if (lane == 0) sm[wv] = m;
    __syncthreads();
    if (threadIdx.x == 0)
        partials[blockIdx.y * gridDim.x + blockIdx.x] =
            fmaxf(fmaxf(sm[0], sm[1]), fmaxf(sm[2], sm[3]));
}

// ---- K7: fused reduce + normalize ----
__global__ void norm_fused(float* __restrict__ out,
                           const float* __restrict__ partials, int N) {
    float m = 0.f;
    for (int i = threadIdx.x; i < 512; i += 256) m = fmaxf(m, partials[i]);
    for (int o = 32; o > 0; o >>= 1) m = fmaxf(m, __shfl_xor(m, o));
    __shared__ float sm[4];
    int lane = threadIdx.x & 63, wv = threadIdx.x >> 6;
    if (lane == 0) sm[wv] = m;
    __syncthreads();
    float inv = 1.0f / fmaxf(fmaxf(sm[0], sm[1]), fmaxf(sm[2], sm[3]));
    int stride = gridDim.x * blockDim.x;
    for (int t = blockIdx.x * blockDim.x + threadIdx.x; t < N; t += stride)
        out[t] *= inv;
}

extern "C" void kernel_launch(void* const* d_in, const int* in_sizes, int n_in,
                              void* d_out, int out_size, void* d_ws, size_t ws_size,
                              hipStream_t stream) {
    const float* audio = (const float*)d_in[0];
    const float* ir    = (const float*)d_in[1];
    float* out = (float*)d_out;

    const int N = in_sizes[0];          // 2,646,000
    const int M = in_sizes[1];          // 220,500
    const int V = L_FFT - M + 1;        // 828,077

    __half2* A = (__half2*)d_ws;                       // 3L half2 = 12.6 MB
    __half2* B = A + (size_t)3 * L_FFT;                // 3L half2
    float* partials = (float*)(B + (size_t)3 * L_FFT);

    const float invLn2 = 1.0f / 4096.0f;

    fwd1_pack<<<dim3(256, 3), 256, 0, stream>>>(audio, ir, B, N, M, V);
    stage256<<<dim3(256, 3), 256, 0, stream>>>(B, A, 256, 8, invLn2);
    fwd3_spectral<<<257, 256, 0, stream>>>(A, B);
    inv1<<<dim3(256, 2), 256, 0, stream>>>(B, A);
    stage256<<<dim3(256, 2), 256, 0, stream>>>(A, B, 256, 8, invLn2);
    inv3_out<<<dim3(256, 2), 256, 0, stream>>>(B, out, partials, N, V);
    norm_fused<<<1024, 256, 0, stream>>>(out, partials, N);
}